// Round 6
// baseline (4777.622 us; speedup 1.0000x reference)
//
#include <hip/hip_runtime.h>
#include <cstdint>

#define TT 512
#define BB 128
#define DD 512
#define HH 512
#define KTOT 1024

typedef short bf16x8 __attribute__((ext_vector_type(8)));
typedef float f32x4 __attribute__((ext_vector_type(4)));
typedef unsigned long long u64t;

__device__ inline unsigned short f2bfs(float f) {
    unsigned int u = __builtin_bit_cast(unsigned int, f);
    u = (u + 0x7FFFu + ((u >> 16) & 1u)) >> 16;
    return (unsigned short)u;
}

__device__ inline float sigf(float x) { return 1.f / (1.f + __expf(-x)); }
__device__ inline float tanhfast(float x) { return 2.f * sigf(2.f * x) - 1.f; }

__device__ inline bf16x8 load8w(const float* p) {
    const float4* p4 = (const float4*)p;
    float4 a = p4[0], b = p4[1];
    bf16x8 r;
    r[0] = (short)f2bfs(a.x); r[1] = (short)f2bfs(a.y);
    r[2] = (short)f2bfs(a.z); r[3] = (short)f2bfs(a.w);
    r[4] = (short)f2bfs(b.x); r[5] = (short)f2bfs(b.y);
    r[6] = (short)f2bfs(b.z); r[7] = (short)f2bfs(b.w);
    return r;
}

// r6: r4 structure (proven 1856us) + latency-overlap scheduling only.
//  - exchange primitive unchanged: per-wave flag word after per-wave
//    s_waitcnt vmcnt(0); one bf16 data sweep after flag-line validates.
//    (Tagged/data-polling regressed twice: r2 +23%, r5 +58%. Do not revisit.)
//  - NEW drain overlap: h-store -> out-store -> next-step x float4 loads ->
//    vmcnt(0) -> flag. Store-ack RT runs concurrently with x-load RT.
//  - NEW: fv flag-line load issues right after flag store; RT filled by
//    the x f2bfs conversions.
//  - NEW: x-part MFMAs run AFTER detect, between h-load issue and h-use,
//    filling the h-load RT window (they were serial shadow work before).
//  - poll is a pure spin: each retry self-throttles at ~1 load RT.
//  - slot-reuse safety (unchanged): P's step-t+1 h-store follows P's
//    validation of flags(t), each of which follows that wave's own h_t
//    read -> pcp -> barrier -> epilogue -> h-store(t) -> drain -> flag(t).
__global__ __launch_bounds__(256, 1) void qlstm_kernel(
    const float* __restrict__ X,
    const float* __restrict__ Wf, const float* __restrict__ bfb,
    const float* __restrict__ Wi, const float* __restrict__ bi,
    const float* __restrict__ Wu, const float* __restrict__ bu,
    const float* __restrict__ Wo, const float* __restrict__ bo,
    const float* __restrict__ Ws1, const float* __restrict__ bs1,
    const float* __restrict__ Ws2, const float* __restrict__ bs2,
    float* __restrict__ out,
    unsigned int* __restrict__ flags,    // [TT][8][128]: one word per producer wave
    unsigned short* __restrict__ hbuf)   // [2][BB][HH] bf16 ping-pong
{
    const int tid  = threadIdx.x;
    const int bid  = blockIdx.x;
    // XCD-local pipelines (speed heuristic; correctness is per-access agent-scope).
    const int rg   = bid & 7;
    const int cg   = bid >> 3;
    const int b0   = rg * 16;
    const int lane = tid & 63;
    const int wv   = tid >> 6;    // wave -> K-slice owner (all 4 gates)
    const int qd   = lane >> 4;
    const int nn   = lane & 15;

    __shared__ float pcp[4][4][16][17];   // [wave][gate][m][n] K-partials, padded

    // ---- one-time: this wave's B-fragments: 4 gates x 8 kk (x:0..3, h:4..7) ----
    bf16x8 wfr[4][8];
    {
        bf16x8 z8;
        #pragma unroll
        for (int j = 0; j < 8; ++j) z8[j] = 0;
        #pragma unroll
        for (int g = 0; g < 4; ++g) {
            const float* Wg = (g == 0) ? Wi : (g == 1) ? Wu : (g == 2) ? Wo : Wf;
            const size_t row = (g == 3) ? (size_t)nn : (size_t)(cg * 16 + nn);
            const bool valid = (g < 3) || (nn < 2);
            #pragma unroll
            for (int j = 0; j < 8; ++j) {
                const int kk = (j < 4) ? (wv * 4 + j) : (16 + wv * 4 + (j - 4));
                wfr[g][j] = valid ? load8w(Wg + row * KTOT + kk * 32 + qd * 8) : z8;
            }
        }
    }

    // ---- one-time: small params (f-head computed redundantly per-thread) ----
    const int fm = tid >> 4, fn = tid & 15;
    const int gcol = cg * 16 + fn;
    const float bir = bi[gcol], bur = bu[gcol], bor = bo[gcol];
    const float bfr0 = bfb[0], bfr1 = bfb[1];
    float ws1r[8], bs1r[4], ws2r[8];
    #pragma unroll
    for (int j = 0; j < 8; ++j) ws1r[j] = Ws1[j];
    #pragma unroll
    for (int j = 0; j < 4; ++j) bs1r[j] = bs1[j];
    #pragma unroll
    for (int j = 0; j < 8; ++j) ws2r[j] = Ws2[j];
    const float bs2r0 = bs2[0], bs2r1 = bs2[1];

    // ---- prologue: x fragments for step 0 (registers) ----
    bf16x8 xa[4];
    #pragma unroll
    for (int j = 0; j < 4; ++j)
        xa[j] = load8w(X + (size_t)(b0 + nn) * DD + (wv * 4 + j) * 32 + qd * 8);

    float cval = 0.f;   // persistent cell state for (fm, fn)
    u64t  fv   = 0;     // pre-issued flag-line word (2 flags)

    for (int t = 0; t < TT; ++t) {
        u64t hw[8];
        // ---- detect h_{t-1} (spin on flag line), then issue h-load sweep ----
        if (t > 0) {
            const u64t* fl = (const u64t*)&flags[((t - 1) * 8 + rg) * 128];
            while (__ballot(((unsigned int)fv == 0u) |
                            ((unsigned int)(fv >> 32) == 0u)) != 0ull) {
                fv = __hip_atomic_load(&fl[lane],
                       __ATOMIC_RELAXED, __HIP_MEMORY_SCOPE_AGENT);
            }
            asm volatile("" ::: "memory");   // pin h-loads after poll pass
            const unsigned short* hb = hbuf
                + (size_t)((t + 1) & 1) * BB * HH + (size_t)(b0 + nn) * HH;
            #pragma unroll
            for (int j = 0; j < 4; ++j) {
                const u64t* bp = (const u64t*)(hb + (wv * 4 + j) * 32 + qd * 8);
                hw[2 * j]     = __hip_atomic_load(bp,
                                  __ATOMIC_RELAXED, __HIP_MEMORY_SCOPE_AGENT);
                hw[2 * j + 1] = __hip_atomic_load(bp + 1,
                                  __ATOMIC_RELAXED, __HIP_MEMORY_SCOPE_AGENT);
            }
        }

        // ---- x-part MFMAs fill the h-load RT window ----
        f32x4 ac[4];
        #pragma unroll
        for (int g = 0; g < 4; ++g) ac[g] = f32x4{0.f, 0.f, 0.f, 0.f};
        #pragma unroll
        for (int j = 0; j < 4; ++j)
            #pragma unroll
            for (int g = 0; g < 4; ++g)
                ac[g] = __builtin_amdgcn_mfma_f32_16x16x32_bf16(xa[j], wfr[g][j], ac[g], 0, 0, 0);

        // ---- h-part: extract fragments (waits the loads), 16 MFMAs ----
        if (t > 0) {
            #pragma unroll
            for (int j = 0; j < 4; ++j) {
                bf16x8 ha;
                ((u64t*)&ha)[0] = hw[2 * j];
                ((u64t*)&ha)[1] = hw[2 * j + 1];
                #pragma unroll
                for (int g = 0; g < 4; ++g)
                    ac[g] = __builtin_amdgcn_mfma_f32_16x16x32_bf16(ha, wfr[g][4 + j], ac[g], 0, 0, 0);
            }
        }

        // ---- publish this wave's K-partials; single rendezvous ----
        #pragma unroll
        for (int g = 0; g < 4; ++g)
            #pragma unroll
            for (int r = 0; r < 4; ++r)
                pcp[wv][g][qd * 4 + r][nn] = ac[g][r];
        __syncthreads();   // (b) pcp complete

        // ---- epilogue: sum 4 partials, f-head MLP+softmax, gate update ----
        float s0g = 0.f, s1g = 0.f, s2g = 0.f, sl0 = 0.f, sl1 = 0.f;
        #pragma unroll
        for (int w = 0; w < 4; ++w) {
            s0g += pcp[w][0][fm][fn];
            s1g += pcp[w][1][fm][fn];
            s2g += pcp[w][2][fm][fn];
            sl0 += pcp[w][3][fm][0];
            sl1 += pcp[w][3][fm][1];
        }
        const float l0 = bfr0 + sl0;
        const float l1 = bfr1 + sl1;
        const float hd0 = tanhfast(ws1r[0] * l0 + ws1r[1] * l1 + bs1r[0]);
        const float hd1 = tanhfast(ws1r[2] * l0 + ws1r[3] * l1 + bs1r[1]);
        const float hd2 = tanhfast(ws1r[4] * l0 + ws1r[5] * l1 + bs1r[2]);
        const float hd3 = tanhfast(ws1r[6] * l0 + ws1r[7] * l1 + bs1r[3]);
        const float s0 = bs2r0 + ws2r[0]*hd0 + ws2r[1]*hd1 + ws2r[2]*hd2 + ws2r[3]*hd3;
        const float s1 = bs2r1 + ws2r[4]*hd0 + ws2r[5]*hd1 + ws2r[6]*hd2 + ws2r[7]*hd3;
        const float fval = sigf(s0 - s1);

        const float iv = sigf(bir + s0g);
        const float gv = tanhfast(bur + s1g);
        const float ov = sigf(bor + s2g);
        cval = fval * cval + iv * gv;
        const float hv = ov * tanhfast(cval);
        const int b = b0 + fm;

        // ---- h-store first (earliest ack), then fill the drain window ----
        {
            unsigned int ub = (unsigned int)f2bfs(hv);
            unsigned int ob = __shfl_xor(ub, 1);
            if ((fn & 1) == 0) {
                unsigned int* hp = (unsigned int*)(hbuf
                    + (size_t)(t & 1) * BB * HH + (size_t)b * HH + gcol);
                __hip_atomic_store(hp, ub | (ob << 16),
                                   __ATOMIC_RELAXED, __HIP_MEMORY_SCOPE_AGENT);
            }
        }
        out[((size_t)t * BB + b) * HH + gcol] = hv;
        if (t == TT - 1) {
            out[(size_t)TT * BB * HH + (size_t)b * HH + gcol] = hv;
            out[(size_t)TT * BB * HH + (size_t)BB * HH + (size_t)b * HH + gcol] = cval;
        }
        // next-step x loads: their RT overlaps the store-ack drain
        const int tn = (t + 1 < TT) ? t + 1 : t;
        float4 xp[8];
        {
            const float* xb = X + ((size_t)tn * BB + b0 + nn) * DD;
            #pragma unroll
            for (int j = 0; j < 4; ++j) {
                const float4* p4 = (const float4*)(xb + (wv * 4 + j) * 32 + qd * 8);
                xp[2 * j]     = p4[0];
                xp[2 * j + 1] = p4[1];
            }
        }
        asm volatile("s_waitcnt vmcnt(0)" ::: "memory");   // h-store acked (x RT merged)
        if (lane == 0)
            __hip_atomic_store(&flags[(t * 8 + rg) * 128 + cg * 4 + wv], 1u,
                               __ATOMIC_RELAXED, __HIP_MEMORY_SCOPE_AGENT);
        // pre-issue next flag-line read; RT filled by the f2bfs below
        fv = __hip_atomic_load(
               &((const u64t*)&flags[(t * 8 + rg) * 128])[lane],
               __ATOMIC_RELAXED, __HIP_MEMORY_SCOPE_AGENT);

        // ---- convert x fragments for t+1 (fills fv RT) ----
        #pragma unroll
        for (int j = 0; j < 4; ++j) {
            float4 a = xp[2 * j], c = xp[2 * j + 1];
            bf16x8 r;
            r[0] = (short)f2bfs(a.x); r[1] = (short)f2bfs(a.y);
            r[2] = (short)f2bfs(a.z); r[3] = (short)f2bfs(a.w);
            r[4] = (short)f2bfs(c.x); r[5] = (short)f2bfs(c.y);
            r[6] = (short)f2bfs(c.z); r[7] = (short)f2bfs(c.w);
            xa[j] = r;
        }
    }
}

extern "C" void kernel_launch(void* const* d_in, const int* in_sizes, int n_in,
                              void* d_out, int out_size, void* d_ws, size_t ws_size,
                              hipStream_t stream) {
    const float* X   = (const float*)d_in[0];
    const float* Wf  = (const float*)d_in[1];
    const float* bfb = (const float*)d_in[2];
    const float* Wi  = (const float*)d_in[3];
    const float* bi  = (const float*)d_in[4];
    const float* Wu  = (const float*)d_in[5];
    const float* bu  = (const float*)d_in[6];
    const float* Wo  = (const float*)d_in[7];
    const float* bo  = (const float*)d_in[8];
    const float* Ws1 = (const float*)d_in[9];
    const float* bs1 = (const float*)d_in[10];
    const float* Ws2 = (const float*)d_in[11];
    const float* bs2 = (const float*)d_in[12];
    float* out = (float*)d_out;

    // flags: [TT][8][128] u32 = 2 MB (per-wave, per-t, never reused);
    // hbuf: [2][BB][HH] bf16 = 256 KB ping-pong (slot0 fully written at t=0
    // before first gated read at t=1; no zeroing needed).
    unsigned int*   flags = (unsigned int*)d_ws;
    unsigned short* hbuf  = (unsigned short*)((char*)d_ws + (size_t)TT * 8 * 128 * 4);

    hipMemsetAsync(d_ws, 0, (size_t)TT * 8 * 128 * 4, stream);
    qlstm_kernel<<<dim3(256), dim3(256), 0, stream>>>(
        X, Wf, bfb, Wi, bi, Wu, bu, Wo, bo, Ws1, bs1, Ws2, bs2, out, flags, hbuf);
}

// Round 7
// 1969.531 us; speedup vs baseline: 2.4258x; 2.4258x over previous
//
#include <hip/hip_runtime.h>
#include <cstdint>

#define TT 512
#define BB 128
#define DD 512
#define HH 512
#define KTOT 1024

typedef short bf16x8 __attribute__((ext_vector_type(8)));
typedef float f32x4 __attribute__((ext_vector_type(4)));
typedef unsigned long long u64t;

__device__ inline unsigned short f2bfs(float f) {
    unsigned int u = __builtin_bit_cast(unsigned int, f);
    u = (u + 0x7FFFu + ((u >> 16) & 1u)) >> 16;
    return (unsigned short)u;
}

__device__ inline float sigf(float x) { return 1.f / (1.f + __expf(-x)); }
__device__ inline float tanhfast(float x) { return 2.f * sigf(2.f * x) - 1.f; }

__device__ inline bf16x8 load8w(const float* p) {
    const float4* p4 = (const float4*)p;
    float4 a = p4[0], b = p4[1];
    bf16x8 r;
    r[0] = (short)f2bfs(a.x); r[1] = (short)f2bfs(a.y);
    r[2] = (short)f2bfs(a.z); r[3] = (short)f2bfs(a.w);
    r[4] = (short)f2bfs(b.x); r[5] = (short)f2bfs(b.y);
    r[6] = (short)f2bfs(b.z); r[7] = (short)f2bfs(b.w);
    return r;
}

// r7 = r4 (proven 1856us) + ONE change: per-wave SLICE waiting.
//  - consumer wave wv only consumes h cols [wv*128, wv*128+128), produced by
//    WGs cg' in [wv*8, wv*8+8) = 32 producer waves = flag words
//    [wv*32, wv*32+32) = exactly ONE 128B line. Each wave polls only that
//    line: max-statistic shrinks 128 -> 32 waves, waves decouple (early
//    waves run h-loads+MFMAs while siblings wait; pcp barrier overlaps
//    laggard waits with peer compute).
//  - slot-reuse safety: a WG's h_{t+1} store follows barrier (b), which
//    follows ALL 4 of its waves' slice validations of flags(t) (union =
//    all 32 producer WGs); each producer-wave flag(t) postdates that
//    wave's h_{t-1} reads. Same transitive happens-before as r4.
//  - r6 lesson (2.5x regression): NEVER put loads between the h-store and
//    its vmcnt(0)+flag — the flag store then waits the load RT and that
//    latency compounds across all 512 steps. Epilogue order here is r4's.
//  - r2/r5 lesson: detect-by-polling-data (tagged words) regressed twice;
//    flag-line detect + single data sweep is the proven primitive.
__global__ __launch_bounds__(256, 1) void qlstm_kernel(
    const float* __restrict__ X,
    const float* __restrict__ Wf, const float* __restrict__ bfb,
    const float* __restrict__ Wi, const float* __restrict__ bi,
    const float* __restrict__ Wu, const float* __restrict__ bu,
    const float* __restrict__ Wo, const float* __restrict__ bo,
    const float* __restrict__ Ws1, const float* __restrict__ bs1,
    const float* __restrict__ Ws2, const float* __restrict__ bs2,
    float* __restrict__ out,
    unsigned int* __restrict__ flags,    // [TT][8][128]: one word per producer wave
    unsigned short* __restrict__ hbuf)   // [2][BB][HH] bf16 ping-pong
{
    const int tid  = threadIdx.x;
    const int bid  = blockIdx.x;
    // XCD-local pipelines (speed heuristic; correctness is per-access agent-scope).
    const int rg   = bid & 7;
    const int cg   = bid >> 3;
    const int b0   = rg * 16;
    const int lane = tid & 63;
    const int wv   = tid >> 6;    // wave -> K-slice owner (all 4 gates)
    const int qd   = lane >> 4;
    const int nn   = lane & 15;

    __shared__ float pcp[4][4][16][17];   // [wave][gate][m][n] K-partials, padded

    // ---- one-time: this wave's B-fragments: 4 gates x 8 kk (x:0..3, h:4..7) ----
    bf16x8 wfr[4][8];
    {
        bf16x8 z8;
        #pragma unroll
        for (int j = 0; j < 8; ++j) z8[j] = 0;
        #pragma unroll
        for (int g = 0; g < 4; ++g) {
            const float* Wg = (g == 0) ? Wi : (g == 1) ? Wu : (g == 2) ? Wo : Wf;
            const size_t row = (g == 3) ? (size_t)nn : (size_t)(cg * 16 + nn);
            const bool valid = (g < 3) || (nn < 2);
            #pragma unroll
            for (int j = 0; j < 8; ++j) {
                const int kk = (j < 4) ? (wv * 4 + j) : (16 + wv * 4 + (j - 4));
                wfr[g][j] = valid ? load8w(Wg + row * KTOT + kk * 32 + qd * 8) : z8;
            }
        }
    }

    // ---- one-time: small params (f-head computed redundantly per-thread) ----
    const int fm = tid >> 4, fn = tid & 15;
    const int gcol = cg * 16 + fn;
    const float bir = bi[gcol], bur = bu[gcol], bor = bo[gcol];
    const float bfr0 = bfb[0], bfr1 = bfb[1];
    float ws1r[8], bs1r[4], ws2r[8];
    #pragma unroll
    for (int j = 0; j < 8; ++j) ws1r[j] = Ws1[j];
    #pragma unroll
    for (int j = 0; j < 4; ++j) bs1r[j] = bs1[j];
    #pragma unroll
    for (int j = 0; j < 8; ++j) ws2r[j] = Ws2[j];
    const float bs2r0 = bs2[0], bs2r1 = bs2[1];

    // ---- prologue "shadow": x-partials for step 0 (held in registers) ----
    f32x4 ac[4];
    #pragma unroll
    for (int g = 0; g < 4; ++g) ac[g] = f32x4{0.f, 0.f, 0.f, 0.f};
    {
        bf16x8 xa[4];
        #pragma unroll
        for (int j = 0; j < 4; ++j)
            xa[j] = load8w(X + (size_t)(b0 + nn) * DD + (wv * 4 + j) * 32 + qd * 8);
        #pragma unroll
        for (int j = 0; j < 4; ++j)
            #pragma unroll
            for (int g = 0; g < 4; ++g)
                ac[g] = __builtin_amdgcn_mfma_f32_16x16x32_bf16(xa[j], wfr[g][j], ac[g], 0, 0, 0);
    }

    float cval = 0.f;          // persistent cell state for (fm, fn)
    unsigned int fvw = 1u;     // pre-issued flag word for THIS wave's slice

    for (int t = 0; t < TT; ++t) {
        // ---- wait for THIS wave's 32 producer-wave flags (one 128B line) ----
        if (t > 0) {
            const unsigned int* fl =
                &flags[((t - 1) * 8 + rg) * 128 + wv * 32];
            while (__ballot(fvw == 0u) != 0ull) {
                __builtin_amdgcn_s_sleep(1);
                fvw = __hip_atomic_load(&fl[lane & 31],
                        __ATOMIC_RELAXED, __HIP_MEMORY_SCOPE_AGENT);
            }
            asm volatile("" ::: "memory");   // pin h-loads after poll pass
            const unsigned short* hb = hbuf
                + (size_t)((t + 1) & 1) * BB * HH + (size_t)(b0 + nn) * HH;
            u64t hwv[8];
            #pragma unroll
            for (int j = 0; j < 4; ++j) {
                const u64t* bp = (const u64t*)(hb + (wv * 4 + j) * 32 + qd * 8);
                hwv[2 * j]     = __hip_atomic_load(bp,
                                   __ATOMIC_RELAXED, __HIP_MEMORY_SCOPE_AGENT);
                hwv[2 * j + 1] = __hip_atomic_load(bp + 1,
                                   __ATOMIC_RELAXED, __HIP_MEMORY_SCOPE_AGENT);
            }
            #pragma unroll
            for (int j = 0; j < 4; ++j) {
                bf16x8 ha;
                ((u64t*)&ha)[0] = hwv[2 * j];
                ((u64t*)&ha)[1] = hwv[2 * j + 1];
                #pragma unroll
                for (int g = 0; g < 4; ++g)
                    ac[g] = __builtin_amdgcn_mfma_f32_16x16x32_bf16(ha, wfr[g][4 + j], ac[g], 0, 0, 0);
            }
        }

        // ---- publish this wave's K-partials; single rendezvous ----
        #pragma unroll
        for (int g = 0; g < 4; ++g)
            #pragma unroll
            for (int r = 0; r < 4; ++r)
                pcp[wv][g][qd * 4 + r][nn] = ac[g][r];
        __syncthreads();   // (b) pcp complete

        // ---- epilogue: sum 4 partials, f-head MLP+softmax, gate update ----
        float s0g = 0.f, s1g = 0.f, s2g = 0.f, sl0 = 0.f, sl1 = 0.f;
        #pragma unroll
        for (int w = 0; w < 4; ++w) {
            s0g += pcp[w][0][fm][fn];
            s1g += pcp[w][1][fm][fn];
            s2g += pcp[w][2][fm][fn];
            sl0 += pcp[w][3][fm][0];
            sl1 += pcp[w][3][fm][1];
        }
        const float l0 = bfr0 + sl0;
        const float l1 = bfr1 + sl1;
        const float hd0 = tanhfast(ws1r[0] * l0 + ws1r[1] * l1 + bs1r[0]);
        const float hd1 = tanhfast(ws1r[2] * l0 + ws1r[3] * l1 + bs1r[1]);
        const float hd2 = tanhfast(ws1r[4] * l0 + ws1r[5] * l1 + bs1r[2]);
        const float hd3 = tanhfast(ws1r[6] * l0 + ws1r[7] * l1 + bs1r[3]);
        const float s0 = bs2r0 + ws2r[0]*hd0 + ws2r[1]*hd1 + ws2r[2]*hd2 + ws2r[3]*hd3;
        const float s1 = bs2r1 + ws2r[4]*hd0 + ws2r[5]*hd1 + ws2r[6]*hd2 + ws2r[7]*hd3;
        const float fval = sigf(s0 - s1);

        const float iv = sigf(bir + s0g);
        const float gv = tanhfast(bur + s1g);
        const float ov = sigf(bor + s2g);
        cval = fval * cval + iv * gv;
        const float hv = ov * tanhfast(cval);
        const int b = b0 + fm;

        // ---- paired 32-bit h store, per-wave drain + flag (NOTHING between) ----
        {
            unsigned int ub = (unsigned int)f2bfs(hv);
            unsigned int ob = __shfl_xor(ub, 1);
            if ((fn & 1) == 0) {
                unsigned int* hp = (unsigned int*)(hbuf
                    + (size_t)(t & 1) * BB * HH + (size_t)b * HH + gcol);
                __hip_atomic_store(hp, ub | (ob << 16),
                                   __ATOMIC_RELAXED, __HIP_MEMORY_SCOPE_AGENT);
            }
        }
        asm volatile("s_waitcnt vmcnt(0)" ::: "memory");   // per-wave drain only
        if (lane == 0)
            __hip_atomic_store(&flags[(t * 8 + rg) * 128 + cg * 4 + wv], 1u,
                               __ATOMIC_RELAXED, __HIP_MEMORY_SCOPE_AGENT);

        // ---- shadow: out stores + x-partials for t+1 + flag pre-issue ----
        out[((size_t)t * BB + b) * HH + gcol] = hv;
        if (t == TT - 1) {
            out[(size_t)TT * BB * HH + (size_t)b * HH + gcol] = hv;
            out[(size_t)TT * BB * HH + (size_t)BB * HH + (size_t)b * HH + gcol] = cval;
        }
        if (t + 1 < TT) {
            #pragma unroll
            for (int g = 0; g < 4; ++g) ac[g] = f32x4{0.f, 0.f, 0.f, 0.f};
            bf16x8 xa[4];
            #pragma unroll
            for (int j = 0; j < 4; ++j)
                xa[j] = load8w(X + ((size_t)(t + 1) * BB + b0 + nn) * DD
                               + (wv * 4 + j) * 32 + qd * 8);
            #pragma unroll
            for (int j = 0; j < 4; ++j)
                #pragma unroll
                for (int g = 0; g < 4; ++g)
                    ac[g] = __builtin_amdgcn_mfma_f32_16x16x32_bf16(xa[j], wfr[g][j], ac[g], 0, 0, 0);
            fvw = __hip_atomic_load(
                    &flags[(t * 8 + rg) * 128 + wv * 32 + (lane & 31)],
                    __ATOMIC_RELAXED, __HIP_MEMORY_SCOPE_AGENT);
        }
    }
}

extern "C" void kernel_launch(void* const* d_in, const int* in_sizes, int n_in,
                              void* d_out, int out_size, void* d_ws, size_t ws_size,
                              hipStream_t stream) {
    const float* X   = (const float*)d_in[0];
    const float* Wf  = (const float*)d_in[1];
    const float* bfb = (const float*)d_in[2];
    const float* Wi  = (const float*)d_in[3];
    const float* bi  = (const float*)d_in[4];
    const float* Wu  = (const float*)d_in[5];
    const float* bu  = (const float*)d_in[6];
    const float* Wo  = (const float*)d_in[7];
    const float* bo  = (const float*)d_in[8];
    const float* Ws1 = (const float*)d_in[9];
    const float* bs1 = (const float*)d_in[10];
    const float* Ws2 = (const float*)d_in[11];
    const float* bs2 = (const float*)d_in[12];
    float* out = (float*)d_out;

    // flags: [TT][8][128] u32 = 2 MB (per-wave, per-t, never reused);
    // hbuf: [2][BB][HH] bf16 = 256 KB ping-pong (slot0 fully written at t=0
    // before first gated read at t=1; no zeroing needed).
    unsigned int*   flags = (unsigned int*)d_ws;
    unsigned short* hbuf  = (unsigned short*)((char*)d_ws + (size_t)TT * 8 * 128 * 4);

    hipMemsetAsync(d_ws, 0, (size_t)TT * 8 * 128 * 4, stream);
    qlstm_kernel<<<dim3(256), dim3(256), 0, stream>>>(
        X, Wf, bfb, Wi, bi, Wu, bu, Wo, bo, Ws1, bs1, Ws2, bs2, out, flags, hbuf);
}